// Round 1
// baseline (276.513 us; speedup 1.0000x reference)
//
#include <hip/hip_runtime.h>

// Shapes (fixed by problem): B=2, T=2048, E=1024, H=16, Hkv=4, D=64, G=4
// window_size = 1024 (read from device mem to be safe)

typedef float f32x4 __attribute__((ext_vector_type(4)));
typedef short s16x8 __attribute__((ext_vector_type(8)));

__device__ __forceinline__ unsigned short f2bf(float f) {
  unsigned u = __float_as_uint(f);
  u += 0x7fffu + ((u >> 16) & 1u);   // round-to-nearest-even
  return (unsigned short)(u >> 16);
}

// ---------------- fp32 -> bf16 convert (vectorized x4) ----------------
__global__ void cvt_bf16(const float* __restrict__ in, unsigned short* __restrict__ out, int n4) {
  int i = blockIdx.x * blockDim.x + threadIdx.x;
  if (i >= n4) return;
  float4 v = ((const float4*)in)[i];
  ushort4 o;
  o.x = f2bf(v.x); o.y = f2bf(v.y); o.z = f2bf(v.z); o.w = f2bf(v.w);
  ((ushort4*)out)[i] = o;
}

// ---------------- bf16 GEMM: C(MxN fp32) = A(MxK) @ B(NxK)^T ----------------
// 128x128 block tile, BK=32, 256 threads = 4 waves (2x2), each wave 64x64 (4x4 of 16x16x32 mfma)
__global__ __launch_bounds__(256) void gemm_bf16(
    const unsigned short* __restrict__ A, const unsigned short* __restrict__ B,
    float* __restrict__ C, int K, int ldc) {
  __shared__ unsigned short As[128 * 40];  // stride 40 elems (80B) to dodge bank conflicts
  __shared__ unsigned short Bs[128 * 40];
  int bn = blockIdx.x, bm = blockIdx.y;
  int t = threadIdx.x;
  int w = t >> 6, lane = t & 63;
  int c = lane & 15, g = lane >> 4;
  int wm = w >> 1, wn = w & 1;

  f32x4 acc[4][4];
#pragma unroll
  for (int i = 0; i < 4; ++i)
#pragma unroll
    for (int j = 0; j < 4; ++j) acc[i][j] = (f32x4){0.f, 0.f, 0.f, 0.f};

  const unsigned short* Ab = A + (size_t)(bm * 128) * K;
  const unsigned short* Bb = B + (size_t)(bn * 128) * K;

  for (int k0 = 0; k0 < K; k0 += 32) {
#pragma unroll
    for (int i = 0; i < 2; ++i) {
      int cid = t + i * 256;          // 512 chunks of 8 bf16
      int rowi = cid >> 2, cg = cid & 3;
      *(s16x8*)(As + rowi * 40 + cg * 8) = *(const s16x8*)(Ab + (size_t)rowi * K + k0 + cg * 8);
      *(s16x8*)(Bs + rowi * 40 + cg * 8) = *(const s16x8*)(Bb + (size_t)rowi * K + k0 + cg * 8);
    }
    __syncthreads();
    s16x8 af[4], bf[4];
#pragma unroll
    for (int mt = 0; mt < 4; ++mt)
      af[mt] = *(const s16x8*)(As + (wm * 64 + mt * 16 + c) * 40 + g * 8);
#pragma unroll
    for (int nt = 0; nt < 4; ++nt)
      bf[nt] = *(const s16x8*)(Bs + (wn * 64 + nt * 16 + c) * 40 + g * 8);
#pragma unroll
    for (int mt = 0; mt < 4; ++mt)
#pragma unroll
      for (int nt = 0; nt < 4; ++nt)
        acc[mt][nt] = __builtin_amdgcn_mfma_f32_16x16x32_bf16(af[mt], bf[nt], acc[mt][nt], 0, 0, 0);
    __syncthreads();
  }
  // C/D layout: col = lane&15, row = (lane>>4)*4 + reg
#pragma unroll
  for (int mt = 0; mt < 4; ++mt)
#pragma unroll
    for (int nt = 0; nt < 4; ++nt)
#pragma unroll
      for (int r = 0; r < 4; ++r) {
        int rowg = bm * 128 + wm * 64 + mt * 16 + g * 4 + r;
        int colg = bn * 128 + wn * 64 + nt * 16 + c;
        C[(size_t)rowg * ldc + colg] = acc[mt][nt][r];
      }
}

// ---------------- post: rope+rmsnorm on q/k, gate+ve on v ----------------
// one block (256 thr = 4 waves) per token; wave handles one head of 64 at a time
__global__ __launch_bounds__(256) void post_qkv(
    const float* __restrict__ qkv, const float* __restrict__ x, const float* __restrict__ ve,
    const float* __restrict__ cosp, const float* __restrict__ sinp, const float* __restrict__ wgate,
    unsigned short* __restrict__ q_r, unsigned short* __restrict__ k_r,
    unsigned short* __restrict__ v_r) {
  int bt = blockIdx.x;
  int b = bt >> 11, t = bt & 2047;
  int w = threadIdx.x >> 6, lane = threadIdx.x & 63;
  const float* row = qkv + (size_t)bt * 1536;
  int dd = lane & 31;
  float cs = cosp[t * 32 + dd];
  float sn = sinp[t * 32 + dd];
  float sgn = (lane < 32) ? 1.f : -1.f;

  // q heads: wave w does heads w, w+4, w+8, w+12  (fold 0.125 attn scale into q)
#pragma unroll
  for (int i = 0; i < 4; ++i) {
    int hh = w + i * 4;
    float val = row[hh * 64 + lane];
    float p = __shfl_xor(val, 32);
    float rr = val * cs + sgn * p * sn;
    float ss = rr * rr;
#pragma unroll
    for (int o = 32; o >= 1; o >>= 1) ss += __shfl_xor(ss, o);
    float sc = rsqrtf(ss * (1.0f / 64.0f) + 1.1920929e-07f);
    q_r[((size_t)(b * 16 + hh) * 2048 + t) * 64 + lane] = f2bf(rr * sc * 0.125f);
  }
  // k head w
  {
    float val = row[1024 + w * 64 + lane];
    float p = __shfl_xor(val, 32);
    float rr = val * cs + sgn * p * sn;
    float ss = rr * rr;
#pragma unroll
    for (int o = 32; o >= 1; o >>= 1) ss += __shfl_xor(ss, o);
    float sc = rsqrtf(ss * (1.0f / 64.0f) + 1.1920929e-07f);
    k_r[((size_t)(b * 4 + w) * 2048 + t) * 64 + lane] = f2bf(rr * sc);
  }
  // v head w: v + 2*sigmoid(x[:32]@Wgate[w]) * ve
  {
    float part = (lane < 32) ? x[(size_t)bt * 1024 + lane] * wgate[w * 32 + lane] : 0.f;
#pragma unroll
    for (int o = 32; o >= 1; o >>= 1) part += __shfl_xor(part, o);
    float gate = 2.f / (1.f + __expf(-part));
    float vv = row[1280 + w * 64 + lane] + gate * ve[(size_t)bt * 256 + w * 64 + lane];
    v_r[((size_t)(b * 4 + w) * 2048 + t) * 64 + lane] = f2bf(vv);
  }
}

// ---------------- flash attention, sliding window ----------------
// grid: b*H*(T/64) blocks; 4 waves/block; wave w handles 16 q rows; 32-key tiles
__global__ __launch_bounds__(256) void attn_kernel(
    const unsigned short* __restrict__ q_r, const unsigned short* __restrict__ k_r,
    const unsigned short* __restrict__ v_r, unsigned short* __restrict__ y_b,
    const int* __restrict__ wptr) {
  const int W = *wptr;
  int bid = blockIdx.x;
  int qt = bid & 31;
  int h = (bid >> 5) & 15;
  int b = bid >> 9;
  int w = threadIdx.x >> 6;
  int lane = threadIdx.x & 63;
  int c = lane & 15, g = lane >> 4;
  int r0 = qt * 64 + w * 16;
  int hkv = h >> 2;

  __shared__ float pl[4][16 * 36];
  float* P = pl[w];

  const unsigned short* qbase = q_r + ((size_t)(b * 16 + h) * 2048 + r0) * 64;
  s16x8 a_lo = *(const s16x8*)(qbase + (size_t)c * 64 + g * 8);
  s16x8 a_hi = *(const s16x8*)(qbase + (size_t)c * 64 + 32 + g * 8);

  const unsigned short* kbase = k_r + (size_t)(b * 4 + hkv) * 2048 * 64;
  const unsigned short* vbase = v_r + (size_t)(b * 4 + hkv) * 2048 * 64;

  float m_i[4] = {-1e30f, -1e30f, -1e30f, -1e30f};
  float l_i[4] = {0.f, 0.f, 0.f, 0.f};
  f32x4 acc[4];
#pragma unroll
  for (int dt = 0; dt < 4; ++dt) acc[dt] = (f32x4){0.f, 0.f, 0.f, 0.f};

  int kt0 = r0 - W;
  if (kt0 < 0) kt0 = 0;

  for (int kt = kt0; kt < r0 + 16; kt += 32) {
    // S = Q @ K^T  (two 16-key halves)
    f32x4 S0 = (f32x4){0.f, 0.f, 0.f, 0.f};
    f32x4 S1 = (f32x4){0.f, 0.f, 0.f, 0.f};
    {
      int key = kt + c; key = key > 2047 ? 2047 : key;
      const unsigned short* kp = kbase + (size_t)key * 64 + g * 8;
      s16x8 b_lo = *(const s16x8*)(kp);
      s16x8 b_hi = *(const s16x8*)(kp + 32);
      S0 = __builtin_amdgcn_mfma_f32_16x16x32_bf16(a_lo, b_lo, S0, 0, 0, 0);
      S0 = __builtin_amdgcn_mfma_f32_16x16x32_bf16(a_hi, b_hi, S0, 0, 0, 0);
    }
    {
      int key = kt + 16 + c; key = key > 2047 ? 2047 : key;
      const unsigned short* kp = kbase + (size_t)key * 64 + g * 8;
      s16x8 b_lo = *(const s16x8*)(kp);
      s16x8 b_hi = *(const s16x8*)(kp + 32);
      S1 = __builtin_amdgcn_mfma_f32_16x16x32_bf16(a_lo, b_lo, S1, 0, 0, 0);
      S1 = __builtin_amdgcn_mfma_f32_16x16x32_bf16(a_hi, b_hi, S1, 0, 0, 0);
    }

    float alpha[4];
#pragma unroll
    for (int r = 0; r < 4; ++r) {
      int rowg = r0 + g * 4 + r;
      int c0 = kt + c, c1 = kt + 16 + c;
      float s0 = (c0 <= rowg && c0 + W >= rowg) ? S0[r] : -1e30f;
      float s1 = (c1 <= rowg && c1 + W >= rowg) ? S1[r] : -1e30f;
      float mx = fmaxf(s0, s1);
      mx = fmaxf(mx, __shfl_xor(mx, 1));
      mx = fmaxf(mx, __shfl_xor(mx, 2));
      mx = fmaxf(mx, __shfl_xor(mx, 4));
      mx = fmaxf(mx, __shfl_xor(mx, 8));
      float mn = fmaxf(m_i[r], mx);
      float al = __expf(m_i[r] - mn);
      m_i[r] = mn;
      float p0 = __expf(s0 - mn);
      float p1 = __expf(s1 - mn);
      float rs = p0 + p1;
      rs += __shfl_xor(rs, 1);
      rs += __shfl_xor(rs, 2);
      rs += __shfl_xor(rs, 4);
      rs += __shfl_xor(rs, 8);
      l_i[r] = l_i[r] * al + rs;
      alpha[r] = al;
      P[(g * 4 + r) * 36 + c] = p0;
      P[(g * 4 + r) * 36 + 16 + c] = p1;
    }
    asm volatile("" ::: "memory");  // order LDS write -> read (same wave, HW in-order DS)

#pragma unroll
    for (int dt = 0; dt < 4; ++dt) {
      f32x4 a = acc[dt];
      a[0] *= alpha[0]; a[1] *= alpha[1]; a[2] *= alpha[2]; a[3] *= alpha[3];
      acc[dt] = a;
    }

    // P (C-layout) -> A-operand layout via LDS; convert to bf16
    s16x8 pf;
    {
      const float* pr = P + c * 36 + g * 8;
#pragma unroll
      for (int j = 0; j < 8; ++j) pf[j] = (short)f2bf(pr[j]);
    }

    int kb[8];
#pragma unroll
    for (int j = 0; j < 8; ++j) {
      int key = kt + g * 8 + j;
      kb[j] = (key > 2047 ? 2047 : key) * 64;
    }
#pragma unroll
    for (int dt = 0; dt < 4; ++dt) {
      s16x8 vf;
#pragma unroll
      for (int j = 0; j < 8; ++j) vf[j] = (short)vbase[(size_t)kb[j] + dt * 16 + c];
      acc[dt] = __builtin_amdgcn_mfma_f32_16x16x32_bf16(pf, vf, acc[dt], 0, 0, 0);
    }
  }

  float inv[4];
#pragma unroll
  for (int r = 0; r < 4; ++r) inv[r] = 1.0f / l_i[r];
#pragma unroll
  for (int dt = 0; dt < 4; ++dt)
#pragma unroll
    for (int r = 0; r < 4; ++r) {
      int rowg = r0 + g * 4 + r;
      y_b[((size_t)(b * 2048 + rowg) * 16 + h) * 64 + dt * 16 + c] = f2bf(acc[dt][r] * inv[r]);
    }
}

extern "C" void kernel_launch(void* const* d_in, const int* in_sizes, int n_in,
                              void* d_out, int out_size, void* d_ws, size_t ws_size,
                              hipStream_t stream) {
  const float* x = (const float*)d_in[0];
  const float* ve = (const float*)d_in[1];
  const float* cosp = (const float*)d_in[2];
  const float* sinp = (const float*)d_in[3];
  const float* Wq = (const float*)d_in[4];
  const float* Wk = (const float*)d_in[5];
  const float* Wv = (const float*)d_in[6];
  const float* Wproj = (const float*)d_in[7];
  const float* Wgate = (const float*)d_in[8];
  const int* wptr = (const int*)d_in[9];

  // workspace layout (bf16 buffers as ushort), ~57 MB total
  unsigned short* xb = (unsigned short*)d_ws;        // 4096x1024
  unsigned short* wqkv = xb + 4194304;               // 1536x1024 (Wq|Wk|Wv rows)
  unsigned short* wpj = wqkv + 1572864;              // 1024x1024
  unsigned short* q_r = wpj + 1048576;               // [B,H,T,D]
  unsigned short* k_r = q_r + 4194304;               // [B,Hkv,T,D]
  unsigned short* v_r = k_r + 1048576;               // [B,Hkv,T,D]
  unsigned short* y_b = v_r + 1048576;               // [B,T,H,D] = 4096x1024
  float* qkv = (float*)(y_b + 4194304);              // 4096x1536 fp32

  cvt_bf16<<<4096, 256, 0, stream>>>(x, xb, 1048576);
  cvt_bf16<<<1024, 256, 0, stream>>>(Wq, wqkv, 262144);
  cvt_bf16<<<256, 256, 0, stream>>>(Wk, wqkv + 1048576, 65536);
  cvt_bf16<<<256, 256, 0, stream>>>(Wv, wqkv + 1310720, 65536);
  cvt_bf16<<<1024, 256, 0, stream>>>(Wproj, wpj, 262144);

  gemm_bf16<<<dim3(12, 32), 256, 0, stream>>>(xb, wqkv, qkv, 1024, 1536);
  post_qkv<<<4096, 256, 0, stream>>>(qkv, x, ve, cosp, sinp, Wgate, q_r, k_r, v_r);
  attn_kernel<<<1024, 256, 0, stream>>>(q_r, k_r, v_r, y_b, wptr);
  gemm_bf16<<<dim3(8, 32), 256, 0, stream>>>(y_b, wpj, (float*)d_out, 1024, 1024);
}